// Round 8
// baseline (983.853 us; speedup 1.0000x reference)
//
#include <hip/hip_runtime.h>
#include <math.h>

#define D_MODEL 512
#define N_LAYERS 4
#define LATENT 1024
#define D_INNER 1024
#define D_STATE 16
#define DT_RANK 32
#define KCONV 4
#define BATCH 4
#define SEQ 1024
#define NTOK (BATCH * SEQ) /* 4096 */
#define PCH 32
#define CLEN 32
#define NCAT 1152  /* merged xproj+dt GEMM N: 1024 dt | 32 B/C | 96 pad */

typedef __attribute__((ext_vector_type(8))) short short8;
typedef __attribute__((ext_vector_type(4))) float floatx4;
typedef unsigned short ushort_t;

// gfx9 s_waitcnt immediates: vmcnt lo[3:0] hi[15:14], expcnt[6:4], lgkm[11:8]
#define WC_VM4   0x0F74  /* vmcnt(4), lgkm/exp free */
#define WC_VM0   0x0F70  /* vmcnt(0) */
#define WC_LGKM0 0xC07F  /* lgkmcnt(0), vm/exp free */

__device__ __forceinline__ ushort_t f2bf(float f) {
    union { float f; unsigned u; } v; v.f = f;
    unsigned r = v.u + 0x7FFFu + ((v.u >> 16) & 1u);  // RNE
    return (ushort_t)(r >> 16);
}
__device__ __forceinline__ float bf2f(ushort_t u) {
    union { unsigned u; float f; } v; v.u = ((unsigned)u) << 16;
    return v.f;
}
// async global -> LDS, 16B per lane (verified width=16 on gfx950, m97).
__device__ __forceinline__ void gll16(const void* g, void* l) {
    __builtin_amdgcn_global_load_lds(
        (const __attribute__((address_space(1))) void*)g,
        (__attribute__((address_space(3))) void*)l, 16, 0, 0);
}

// ---------------------------------------------------------------------------
// bf16 MFMA GEMM: C[M,N] = A[M,K](bf16) @ Bt[N,K](bf16)^T (+bias)(+C)
// flags: 1 = add bias[n], 2 = accumulate into C (fp32),
//        4 = merged-dt epilogue: n<1024 -> v = softplus(v + bias[n]),
//        8 = write bf16 output to Cb instead of fp32 C.
// BM=BN=128, BK=32, 256 threads (4 waves), wave = 64x64 via 4x4 MFMAs.
//
// K-loop (AITER-style, fine-grained vmcnt — NEVER a full drain at the
// barrier): issue next-tile DMA (4 global_load_lds), then vmcnt(4) waits
// only for the CURRENT tile's 4 oldest DMAs while the new 4 stay in
// flight across the barrier. Second barrier (after lgkmcnt(0)) makes all
// waves' LDS reads of buf[cur] complete before the next iteration's DMA
// overwrites it. Raw s_barrier (no compiler vmcnt(0) drain).
// ---------------------------------------------------------------------------
__global__ __launch_bounds__(256) void gemm_bf16_kernel(
    const ushort_t* __restrict__ A, int lda,
    const ushort_t* __restrict__ Bt, int ldb,
    float* __restrict__ C, ushort_t* __restrict__ Cb, int ldc,
    const float* __restrict__ bias,
    int M, int N, int K, int flags)
{
    __shared__ ushort_t As[2][128 * 32];
    __shared__ ushort_t Bs[2][128 * 32];
    const int tid = threadIdx.x;
    const int m0 = blockIdx.y * 128;
    const int n0 = blockIdx.x * 128;
    const int w = tid >> 6;
    const int lane = tid & 63;
    const int quad = lane >> 4;
    const int l16 = lane & 15;
    const int wm = (w & 1) * 64;
    const int wn = (w >> 1) * 64;

    // staging source: thread tid covers row (tid>>2), cols (tid&3)*8..+7
    const ushort_t* ga = A + (size_t)(m0 + (tid >> 2)) * lda + (tid & 3) * 8;
    const ushort_t* gb = Bt + (size_t)(n0 + (tid >> 2)) * ldb + (tid & 3) * 8;
    const size_t a64 = (size_t)64 * lda, b64 = (size_t)64 * ldb;
    const int lofs = tid * 8;  // LDS element offset (16B/lane, wave-contiguous)

    floatx4 acc[4][4] = {};
    const int nt = K >> 5;

    // prologue: tile 0 -> buf 0 (4 outstanding)
    gll16(ga, &As[0][lofs]);
    gll16(ga + a64, &As[0][2048 + lofs]);
    gll16(gb, &Bs[0][lofs]);
    gll16(gb + b64, &Bs[0][2048 + lofs]);

    for (int kt = 0; kt < nt; kt++) {
        const int cur = kt & 1;
        if (kt + 1 < nt) {
            const ushort_t* pa = ga + (kt + 1) * 32;
            const ushort_t* pb = gb + (kt + 1) * 32;
            gll16(pa, &As[1 - cur][lofs]);
            gll16(pa + a64, &As[1 - cur][2048 + lofs]);
            gll16(pb, &Bs[1 - cur][lofs]);
            gll16(pb + b64, &Bs[1 - cur][2048 + lofs]);
            __builtin_amdgcn_s_waitcnt(WC_VM4);  // tile kt landed; 4 newer in flight
        } else {
            __builtin_amdgcn_s_waitcnt(WC_VM0);
        }
        __builtin_amdgcn_s_barrier();

        short8 af[4], bfr[4];
        #pragma unroll
        for (int i = 0; i < 4; i++)
            af[i] = *(const short8*)&As[cur][(wm + i * 16 + l16) * 32 + quad * 8];
        #pragma unroll
        for (int j = 0; j < 4; j++)
            bfr[j] = *(const short8*)&Bs[cur][(wn + j * 16 + l16) * 32 + quad * 8];
        __builtin_amdgcn_s_waitcnt(WC_LGKM0);    // my LDS reads complete
        __builtin_amdgcn_s_barrier();            // everyone's complete -> buf reusable

        #pragma unroll
        for (int i = 0; i < 4; i++)
            #pragma unroll
            for (int j = 0; j < 4; j++)
                acc[i][j] = __builtin_amdgcn_mfma_f32_16x16x32_bf16(
                    af[i], bfr[j], acc[i][j], 0, 0, 0);
    }

    // C/D layout (m89-verified): col = lane&15, row = quad*4 + reg.
    #pragma unroll
    for (int j = 0; j < 4; j++) {
        int n = n0 + wn + j * 16 + l16;
        float bv = (flags & 1) ? bias[n] : 0.f;
        bool do_sp = (flags & 4) && (n < 1024);
        float spb = do_sp ? bias[n] : 0.f;
        #pragma unroll
        for (int i = 0; i < 4; i++) {
            int mrow = m0 + wm + i * 16 + quad * 4;
            #pragma unroll
            for (int rr = 0; rr < 4; rr++) {
                size_t idx = (size_t)(mrow + rr) * ldc + n;
                float v = acc[i][j][rr] + bv;
                if (do_sp) {
                    v += spb;
                    v = (v > 20.f) ? v : log1pf(__expf(v));
                }
                if (flags & 8) {
                    Cb[idx] = f2bf(v);
                } else {
                    if (flags & 2) v += C[idx];
                    C[idx] = v;
                }
            }
        }
    }
}

// ---------------------------------------------------------------------------
// build_wdt: Wcat rows 0..1023 = (xw[:, :32] @ dt_w)^T, bf16 [n][k].
// ---------------------------------------------------------------------------
__global__ __launch_bounds__(256) void build_wdt_kernel(
    const float* __restrict__ xproj_w, const float* __restrict__ dt_w,
    ushort_t* __restrict__ wcat)
{
    const int l = blockIdx.z;
    const int n0 = blockIdx.x * 64;
    const int k0 = blockIdx.y * 64;
    const float* xw  = xproj_w + (size_t)l * D_INNER * 64;
    const float* dtw = dt_w + (size_t)l * DT_RANK * D_INNER;

    __shared__ float xs[64][33];   // [k][r]
    __shared__ float ds[32][65];   // [r][n]

    const int tid = threadIdx.x;
    {
        int row = tid >> 2;
        int col = (tid & 3) * 8;
        #pragma unroll
        for (int q = 0; q < 8; q++)
            xs[row][col + q] = xw[(size_t)(k0 + row) * 64 + col + q];
    }
    {
        int row = tid >> 3;
        int col = (tid & 7) * 8;
        #pragma unroll
        for (int q = 0; q < 8; q++)
            ds[row][col + q] = dtw[(size_t)row * D_INNER + n0 + col + q];
    }
    __syncthreads();

    const int ty = tid & 15;
    const int tx = tid >> 4;
    float acc[4][4] = {};
    #pragma unroll
    for (int r = 0; r < 32; r++) {
        float a[4], b[4];
        #pragma unroll
        for (int i = 0; i < 4; i++) a[i] = xs[ty * 4 + i][r];
        #pragma unroll
        for (int j = 0; j < 4; j++) b[j] = ds[r][tx * 4 + j];
        #pragma unroll
        for (int j = 0; j < 4; j++)
            #pragma unroll
            for (int i = 0; i < 4; i++)
                acc[j][i] = fmaf(a[i], b[j], acc[j][i]);
    }
    #pragma unroll
    for (int j = 0; j < 4; j++) {
        int n = n0 + tx * 4 + j;
        ushort4 o;
        o.x = f2bf(acc[j][0]); o.y = f2bf(acc[j][1]);
        o.z = f2bf(acc[j][2]); o.w = f2bf(acc[j][3]);
        *(ushort4*)&wcat[((size_t)l * NCAT + n) * D_INNER + k0 + ty * 4] = o;
    }
}

// ---------------------------------------------------------------------------
// build_wbc: Wcat rows 1024..1151: j<32 -> xw[k][32+j] cast; else zero pad.
// (Pad MUST be written every launch: d_ws is re-poisoned to 0xAA.)
// ---------------------------------------------------------------------------
__global__ __launch_bounds__(256) void build_wbc_kernel(
    const float* __restrict__ xproj_w, ushort_t* __restrict__ wcat)
{
    const int idx = blockIdx.x * 256 + threadIdx.x;
    const int k = idx & 1023;
    const int j = (idx >> 10) & 127;
    const int l = idx >> 17;
    ushort_t v = 0;
    if (j < 32)
        v = f2bf(xproj_w[((size_t)l * D_INNER + k) * 64 + 32 + j]);
    wcat[((size_t)l * NCAT + 1024 + j) * D_INNER + k] = v;
}

// ---------------------------------------------------------------------------
__global__ __launch_bounds__(256) void transpose_cast_kernel(
    const float* __restrict__ in, ushort_t* __restrict__ out, int K, int N)
{
    __shared__ float tile[32][33];
    const int n0 = blockIdx.x * 32, k0 = blockIdx.y * 32;
    const int tx = threadIdx.x & 31, ty = threadIdx.x >> 5;
    #pragma unroll
    for (int i = 0; i < 4; i++)
        tile[ty + i * 8][tx] = in[(size_t)(k0 + ty + i * 8) * N + n0 + tx];
    __syncthreads();
    #pragma unroll
    for (int i = 0; i < 4; i++)
        out[(size_t)(n0 + ty + i * 8) * K + k0 + tx] = f2bf(tile[tx][ty + i * 8]);
}

// ---------------------------------------------------------------------------
__global__ __launch_bounds__(256) void cast_bf16_kernel(
    const float* __restrict__ in, ushort_t* __restrict__ out)
{
    const int i = blockIdx.x * 256 + threadIdx.x;
    out[i] = f2bf(in[i]);
}

// ---------------------------------------------------------------------------
__global__ __launch_bounds__(256) void rmsnorm_kernel(
    const float* __restrict__ x, const float* __restrict__ w,
    ushort_t* __restrict__ y)
{
    const int row = blockIdx.x;
    const float* xr = x + (size_t)row * D_MODEL;
    ushort_t* yr = y + (size_t)row * D_MODEL;
    const int tid = threadIdx.x;

    float v0 = xr[tid], v1 = xr[tid + 256];
    float ss = v0 * v0 + v1 * v1;
    #pragma unroll
    for (int off = 32; off > 0; off >>= 1) ss += __shfl_down(ss, off);

    __shared__ float wsum[4];
    __shared__ float scale_s;
    int wid = tid >> 6, lane = tid & 63;
    if (lane == 0) wsum[wid] = ss;
    __syncthreads();
    if (tid == 0) {
        float tot = wsum[0] + wsum[1] + wsum[2] + wsum[3];
        scale_s = 1.0f / sqrtf(tot / (float)D_MODEL + 1e-5f);
    }
    __syncthreads();
    float sc = scale_s;
    yr[tid] = f2bf(v0 * sc * w[tid]);
    yr[tid + 256] = f2bf(v1 * sc * w[tid + 256]);
}

// ---------------------------------------------------------------------------
// Causal dwconv (K=4) + bias + silu. Reads bf16 xz (stride 2048, xp plane),
// writes bf16 u.
// ---------------------------------------------------------------------------
__global__ __launch_bounds__(256) void conv_silu_kernel(
    const ushort_t* __restrict__ xz, const float* __restrict__ w,
    const float* __restrict__ bconv, ushort_t* __restrict__ outb)
{
    const int idx = blockIdx.x * 256 + threadIdx.x;
    const int d = idx & (D_INNER - 1);
    const int t = (idx >> 10) & (SEQ - 1);
    const int row = idx >> 10;
    const ushort_t* base = xz + (size_t)row * 2048 + d;

    float s = 0.f;
    #pragma unroll
    for (int k = 0; k < KCONV; k++) {
        int tt = t + k - (KCONV - 1);
        if (tt >= 0)
            s = fmaf(bf2f(base[(ptrdiff_t)(k - (KCONV - 1)) * 2048]), w[d * KCONV + k], s);
    }
    s += bconv[d];
    float r = s / (1.f + __expf(-s));
    outb[idx] = f2bf(r);
}

// ---------------------------------------------------------------------------
// Chunked selective scan (3 passes), CLEN=32. dt/B/C in dbl (stride NCAT):
// dbl[row][d]=softplus'ed dt; dbl[row][1024+n]=B[n]; dbl[row][1040+n]=C[n].
// u is bf16 in xb; z is bf16 in xz[:,1024:].
// ---------------------------------------------------------------------------
__global__ __launch_bounds__(256) void scan_pass1(
    const float* __restrict__ dbl, const ushort_t* __restrict__ ub,
    const float* __restrict__ A_log,
    float* __restrict__ hfin, float* __restrict__ sumdt)
{
    const int tid = threadIdx.x;
    const int b = blockIdx.x >> 7;
    const int p = (blockIdx.x >> 2) & 31;
    const int d = ((blockIdx.x & 3) << 8) + tid;
    const int t0 = p * CLEN;

    float A[D_STATE];
    #pragma unroll
    for (int n = 0; n < D_STATE; n++) A[n] = -expf(A_log[d * D_STATE + n]);

    float h[D_STATE] = {};
    float sdt = 0.f;

    const float* dtp = dbl + ((size_t)b * SEQ + t0) * NCAT + d;
    const float* bp  = dbl + ((size_t)b * SEQ + t0) * NCAT + 1024;
    const ushort_t* up = ub + ((size_t)b * SEQ + t0) * D_INNER + d;

    for (int t = 0; t < CLEN; t++) {
        float dtv = dtp[(size_t)t * NCAT];
        float uv  = bf2f(up[(size_t)t * D_INNER]);
        float dtu = dtv * uv;
        sdt += dtv;
        #pragma unroll
        for (int n = 0; n < D_STATE; n++)
            h[n] = fmaf(__expf(dtv * A[n]), h[n], dtu * bp[t * NCAT + n]);
    }

    size_t base = (size_t)(b * PCH + p) * D_STATE * D_INNER + d;
    #pragma unroll
    for (int n = 0; n < D_STATE; n++) hfin[base + (size_t)n * D_INNER] = h[n];
    sumdt[(size_t)(b * PCH + p) * D_INNER + d] = sdt;
}

__global__ __launch_bounds__(256) void scan_pass2(
    const float* __restrict__ A_log, const float* __restrict__ sumdt,
    float* __restrict__ hc)
{
    const int tid = threadIdx.x;
    const int b = blockIdx.x >> 6;
    const int n = (blockIdx.x >> 2) & 15;
    const int d = ((blockIdx.x & 3) << 8) + tid;

    const float Aval = -expf(A_log[d * D_STATE + n]);
    float h = 0.f;
    for (int p = 0; p < PCH; p++) {
        size_t idx = ((size_t)(b * PCH + p) * D_STATE + n) * D_INNER + d;
        float fin = hc[idx];
        hc[idx] = h;
        h = fmaf(__expf(Aval * sumdt[(size_t)(b * PCH + p) * D_INNER + d]), h, fin);
    }
}

// pass3: u (bf16, in ub) read then overwritten IN PLACE with y*silu(z).
__global__ __launch_bounds__(256) void scan_pass3(
    const float* __restrict__ dbl, const ushort_t* __restrict__ xz,
    const float* __restrict__ A_log, const float* __restrict__ Dp,
    const float* __restrict__ hstart, ushort_t* ub)
{
    const int tid = threadIdx.x;
    const int b = blockIdx.x >> 7;
    const int p = (blockIdx.x >> 2) & 31;
    const int d = ((blockIdx.x & 3) << 8) + tid;
    const int t0 = p * CLEN;

    float A[D_STATE];
    #pragma unroll
    for (int n = 0; n < D_STATE; n++) A[n] = -expf(A_log[d * D_STATE + n]);
    const float Dv = Dp[d];

    float h[D_STATE];
    size_t base = (size_t)(b * PCH + p) * D_STATE * D_INNER + d;
    #pragma unroll
    for (int n = 0; n < D_STATE; n++) h[n] = hstart[base + (size_t)n * D_INNER];

    const float* dtp = dbl + ((size_t)b * SEQ + t0) * NCAT + d;
    const float* bp  = dbl + ((size_t)b * SEQ + t0) * NCAT + 1024;
    const ushort_t* zp = xz + ((size_t)b * SEQ + t0) * 2048 + 1024 + d;
    ushort_t* up = ub + ((size_t)b * SEQ + t0) * D_INNER + d;

    for (int t = 0; t < CLEN; t++) {
        float dtv = dtp[(size_t)t * NCAT];
        float uv  = bf2f(up[(size_t)t * D_INNER]);
        float zv  = bf2f(zp[(size_t)t * 2048]);
        float dtu = dtv * uv;
        float y = 0.f;
        #pragma unroll
        for (int n = 0; n < D_STATE; n++) {
            h[n] = fmaf(__expf(dtv * A[n]), h[n], dtu * bp[t * NCAT + n]);
            y = fmaf(h[n], bp[t * NCAT + 16 + n], y);
        }
        float res = fmaf(uv, Dv, y);
        res *= zv / (1.f + __expf(-zv));
        up[(size_t)t * D_INNER] = f2bf(res);
    }
}

// ---------------------------------------------------------------------------
__global__ __launch_bounds__(256) void softmax_kernel(
    const float* __restrict__ in, float* __restrict__ out)
{
    const int idx = blockIdx.x * 256 + threadIdx.x;
    float v = in[idx];
    float m = v;
    #pragma unroll
    for (int off = 16; off > 0; off >>= 1) m = fmaxf(m, __shfl_xor(m, off, 32));
    float e = expf(v - m);
    float s = e;
    #pragma unroll
    for (int off = 16; off > 0; off >>= 1) s += __shfl_xor(s, off, 32);
    out[idx] = e / s;
}

// ---------------------------------------------------------------------------
extern "C" void kernel_launch(void* const* d_in, const int* in_sizes, int n_in,
                              void* d_out, int out_size, void* d_ws, size_t ws_size,
                              hipStream_t stream)
{
    const float* x       = (const float*)d_in[0];
    const float* lin1_w  = (const float*)d_in[1];
    const float* lin1_b  = (const float*)d_in[2];
    const float* norm_w  = (const float*)d_in[3];
    const float* in_w    = (const float*)d_in[4];
    const float* conv_w  = (const float*)d_in[5];
    const float* conv_b  = (const float*)d_in[6];
    const float* xproj_w = (const float*)d_in[7];
    const float* dt_w    = (const float*)d_in[8];
    const float* dt_b    = (const float*)d_in[9];
    const float* A_log   = (const float*)d_in[10];
    const float* Dp      = (const float*)d_in[11];
    const float* out_w   = (const float*)d_in[12];
    const float* lin2_w  = (const float*)d_in[13];
    const float* lin2_b  = (const float*)d_in[14];
    float* outp = (float*)d_out;
    (void)ws_size; (void)in_sizes; (void)n_in; (void)out_size;

    float* ws = (float*)d_ws;
    const size_t F1M = 1u << 20;
    float* h     = ws;                        // 2M fl
    float* dbl   = h + 2 * F1M;               // 4.5M fl (also lin2 logits)
    float* sumdt = dbl + (size_t)NTOK * NCAT; // 128K fl
    float* hfin  = sumdt + (size_t)BATCH * PCH * D_INNER; // 2M fl
    ushort_t* xzb   = (ushort_t*)(hfin + 2 * F1M);        // 8M us (xp|z, 2048)
    ushort_t* hn_bf = xzb + 8 * F1M;                      // 2M us
    ushort_t* xb    = hn_bf + 2 * F1M;                    // 4M us
    ushort_t* lin1_wt = xb + 4 * F1M;                     // 512*1024
    ushort_t* in_wt   = lin1_wt + (size_t)512 * 1024;     // 4*2048*512
    ushort_t* out_wt  = in_wt + (size_t)4 * 2048 * 512;   // 4*512*1024
    ushort_t* lin2_wt = out_wt + (size_t)4 * 512 * 1024;  // 1024*512
    ushort_t* wcat    = lin2_wt + (size_t)1024 * 512;     // 4*1152*1024

    dim3 blk(256);

    // --- weight prep ---
    transpose_cast_kernel<<<dim3(512 / 32, 1024 / 32), blk, 0, stream>>>(
        lin1_w, lin1_wt, LATENT, D_MODEL);
    for (int l = 0; l < N_LAYERS; l++) {
        transpose_cast_kernel<<<dim3(2048 / 32, 512 / 32), blk, 0, stream>>>(
            in_w + (size_t)l * 512 * 2048, in_wt + (size_t)l * 2048 * 512, 512, 2048);
        transpose_cast_kernel<<<dim3(512 / 32, 1024 / 32), blk, 0, stream>>>(
            out_w + (size_t)l * 1024 * 512, out_wt + (size_t)l * 512 * 1024, 1024, 512);
    }
    transpose_cast_kernel<<<dim3(1024 / 32, 512 / 32), blk, 0, stream>>>(
        lin2_w, lin2_wt, D_MODEL, LATENT);
    build_wdt_kernel<<<dim3(16, 16, N_LAYERS), blk, 0, stream>>>(
        xproj_w, dt_w, wcat);
    build_wbc_kernel<<<dim3((N_LAYERS * 128 * 1024) / 256), blk, 0, stream>>>(
        xproj_w, wcat);

    // x -> bf16
    cast_bf16_kernel<<<dim3((NTOK * LATENT) / 256), blk, 0, stream>>>(x, xb);

    // lin1: h = x_bf @ lin1_wt^T + b  (fp32 out)
    gemm_bf16_kernel<<<dim3(D_MODEL / 128, NTOK / 128), blk, 0, stream>>>(
        xb, LATENT, lin1_wt, LATENT, h, nullptr, D_MODEL, lin1_b,
        NTOK, D_MODEL, LATENT, 1);

    for (int l = 0; l < N_LAYERS; l++) {
        const float* nw = norm_w + (size_t)l * D_MODEL;
        const float* cw = conv_w + (size_t)l * D_INNER * KCONV;
        const float* cb = conv_b + (size_t)l * D_INNER;
        const float* db = dt_b + (size_t)l * D_INNER;
        const float* al = A_log + (size_t)l * D_INNER * D_STATE;
        const float* dp = Dp + (size_t)l * D_INNER;
        const ushort_t* iwt = in_wt + (size_t)l * 2048 * 512;
        const ushort_t* owt = out_wt + (size_t)l * 512 * 1024;
        const ushort_t* wc  = wcat + (size_t)l * NCAT * D_INNER;

        rmsnorm_kernel<<<dim3(NTOK), blk, 0, stream>>>(h, nw, hn_bf);

        // fused in-proj: xzb = hn @ in_w[l]  (N=2048, bf16 out, 512 blocks)
        gemm_bf16_kernel<<<dim3(2048 / 128, NTOK / 128), blk, 0, stream>>>(
            hn_bf, D_MODEL, iwt, D_MODEL, nullptr, xzb, 2048, nullptr,
            NTOK, 2048, D_MODEL, 8);

        // conv + silu: xzb[:, :1024] -> xb (bf16 u)
        conv_silu_kernel<<<dim3((NTOK * D_INNER) / 256), blk, 0, stream>>>(
            xzb, cw, cb, xb);

        // merged xproj+dt GEMM: dbl[:, :1024]=softplus(u@Wdt+dt_b),
        //                       dbl[:, 1024:1056]=B|C   (fp32 out)
        gemm_bf16_kernel<<<dim3(NCAT / 128, NTOK / 128), blk, 0, stream>>>(
            xb, D_INNER, wc, D_INNER, dbl, nullptr, NCAT, db,
            NTOK, NCAT, D_INNER, 4);

        // chunked scan; pass3 overwrites xb in place with y*silu(z)
        scan_pass1<<<dim3(BATCH * PCH * (D_INNER / 256)), blk, 0, stream>>>(
            dbl, xb, al, hfin, sumdt);
        scan_pass2<<<dim3(BATCH * D_STATE * (D_INNER / 256)), blk, 0, stream>>>(
            al, sumdt, hfin);
        scan_pass3<<<dim3(BATCH * PCH * (D_INNER / 256)), blk, 0, stream>>>(
            dbl, xzb, al, dp, hfin, xb);

        // h += y_bf @ out_wt^T  (fp32 accumulate)
        gemm_bf16_kernel<<<dim3(D_MODEL / 128, NTOK / 128), blk, 0, stream>>>(
            xb, D_INNER, owt, D_INNER, h, nullptr, D_MODEL, nullptr,
            NTOK, D_MODEL, D_INNER, 2);
    }

    // h -> bf16, lin2 (logits into dbl), softmax
    cast_bf16_kernel<<<dim3((NTOK * D_MODEL) / 256), blk, 0, stream>>>(h, xb);
    gemm_bf16_kernel<<<dim3(LATENT / 128, NTOK / 128), blk, 0, stream>>>(
        xb, D_MODEL, lin2_wt, D_MODEL, dbl, nullptr, LATENT, lin2_b,
        NTOK, LATENT, D_MODEL, 1);
    softmax_kernel<<<dim3((NTOK * LATENT) / 256), blk, 0, stream>>>(dbl, outp);
}

// Round 9
// 782.824 us; speedup vs baseline: 1.2568x; 1.2568x over previous
//
#include <hip/hip_runtime.h>
#include <math.h>

#define D_MODEL 512
#define N_LAYERS 4
#define LATENT 1024
#define D_INNER 1024
#define D_STATE 16
#define DT_RANK 32
#define KCONV 4
#define BATCH 4
#define SEQ 1024
#define NTOK (BATCH * SEQ) /* 4096 */
#define PCH 32
#define CLEN 32
#define NCAT 1152  /* merged xproj+dt GEMM N: 1024 dt | 32 B/C | 96 pad */

typedef __attribute__((ext_vector_type(8))) short short8;
typedef __attribute__((ext_vector_type(4))) float floatx4;
typedef unsigned short ushort_t;

// gfx9 s_waitcnt immediates: vmcnt lo[3:0] hi[15:14], expcnt[6:4], lgkm[11:8]
#define WC_VM4   0x0F74  /* vmcnt(4), lgkm/exp free */
#define WC_VM0   0x0F70  /* vmcnt(0) */
#define WC_LGKM0 0xC07F  /* lgkmcnt(0), vm/exp free */

__device__ __forceinline__ ushort_t f2bf(float f) {
    union { float f; unsigned u; } v; v.f = f;
    unsigned r = v.u + 0x7FFFu + ((v.u >> 16) & 1u);  // RNE
    return (ushort_t)(r >> 16);
}
__device__ __forceinline__ float bf2f(ushort_t u) {
    union { unsigned u; float f; } v; v.u = ((unsigned)u) << 16;
    return v.f;
}
// async global -> LDS, 16B per lane (verified width=16 on gfx950, m97).
__device__ __forceinline__ void gll16(const void* g, void* l) {
    __builtin_amdgcn_global_load_lds(
        (const __attribute__((address_space(1))) void*)g,
        (__attribute__((address_space(3))) void*)l, 16, 0, 0);
}

// ---------------------------------------------------------------------------
// bf16 MFMA GEMM: C[M,N] = A[M,K](bf16) @ Bt[N,K](bf16)^T (+bias)(+C)
// flags: 1 = add bias[n], 2 = accumulate into C (fp32),
//        4 = merged-dt epilogue: n<1024 -> v = softplus(v + bias[n]),
//        8 = write bf16 output to Cb instead of fp32 C.
//
// Tile 64x64, BK=64, 256 threads (4 waves 2x2), wave = 32x32 via 2x2 MFMAs
// over 2 k-slices. Sized for RESIDENCY: grids of N/64 x M/64 give 2-8
// blocks/CU on our shapes (vs 0.5-2 at 128-tile) -> cross-block overlap
// hides the K-loop barrier/DMA latency (m114). LDS 32 KB/block (5/CU);
// launch_bounds(256,4) caps VGPR<=128 for >=4 blocks/CU.
//
// LDS layout per buffer: [ks][row][32] (ks = k-half). Row stride 64 B keeps
// the ds_read_b128 bank pattern at the proven 128-tile conflict level, and
// the DMA dest stays wave-uniform base + lane*16B (required, m104/m108).
// ---------------------------------------------------------------------------
__global__ __launch_bounds__(256, 4) void gemm_bf16_kernel(
    const ushort_t* __restrict__ A, int lda,
    const ushort_t* __restrict__ Bt, int ldb,
    float* __restrict__ C, ushort_t* __restrict__ Cb, int ldc,
    const float* __restrict__ bias,
    int M, int N, int K, int flags)
{
    __shared__ ushort_t As[2][4096];  // [buf][ks*2048 + row*32 + col]
    __shared__ ushort_t Bs[2][4096];
    const int tid = threadIdx.x;
    const int m0 = blockIdx.y * 64;
    const int n0 = blockIdx.x * 64;
    const int w = tid >> 6;
    const int lane = tid & 63;
    const int quad = lane >> 4;
    const int l16 = lane & 15;
    const int wm = (w & 1) * 32;
    const int wn = (w >> 1) * 32;

    // staging: thread tid covers row (tid>>2) (all 64 rows), k-col (tid&3)*8
    // within a 32-wide k-half; per matrix 2 DMAs (ks=0,1).
    const ushort_t* ga = A + (size_t)(m0 + (tid >> 2)) * lda + (tid & 3) * 8;
    const ushort_t* gb = Bt + (size_t)(n0 + (tid >> 2)) * ldb + (tid & 3) * 8;
    const int lofs = tid * 8;  // dest: wave-uniform base + lane*16B

    floatx4 acc[2][2] = {};
    const int nt = K >> 6;

    // prologue: tile 0 -> buf 0 (4 outstanding)
    gll16(ga, &As[0][lofs]);
    gll16(ga + 32, &As[0][2048 + lofs]);
    gll16(gb, &Bs[0][lofs]);
    gll16(gb + 32, &Bs[0][2048 + lofs]);

    for (int kt = 0; kt < nt; kt++) {
        const int cur = kt & 1;
        if (kt + 1 < nt) {
            const ushort_t* pa = ga + (kt + 1) * 64;
            const ushort_t* pb = gb + (kt + 1) * 64;
            gll16(pa, &As[1 - cur][lofs]);
            gll16(pa + 32, &As[1 - cur][2048 + lofs]);
            gll16(pb, &Bs[1 - cur][lofs]);
            gll16(pb + 32, &Bs[1 - cur][2048 + lofs]);
            __builtin_amdgcn_s_waitcnt(WC_VM4);  // tile kt landed; 4 newer in flight
        } else {
            __builtin_amdgcn_s_waitcnt(WC_VM0);
        }
        __builtin_amdgcn_s_barrier();

        short8 af[2][2], bfr[2][2];
        #pragma unroll
        for (int ks = 0; ks < 2; ks++) {
            #pragma unroll
            for (int i = 0; i < 2; i++)
                af[ks][i] = *(const short8*)&As[cur][ks * 2048 + (wm + i * 16 + l16) * 32 + quad * 8];
            #pragma unroll
            for (int j = 0; j < 2; j++)
                bfr[ks][j] = *(const short8*)&Bs[cur][ks * 2048 + (wn + j * 16 + l16) * 32 + quad * 8];
        }
        __builtin_amdgcn_s_waitcnt(WC_LGKM0);    // my LDS reads complete
        __builtin_amdgcn_s_barrier();            // everyone's complete -> buf reusable

        #pragma unroll
        for (int ks = 0; ks < 2; ks++)
            #pragma unroll
            for (int i = 0; i < 2; i++)
                #pragma unroll
                for (int j = 0; j < 2; j++)
                    acc[i][j] = __builtin_amdgcn_mfma_f32_16x16x32_bf16(
                        af[ks][i], bfr[ks][j], acc[i][j], 0, 0, 0);
    }

    // C/D layout (m89-verified): col = lane&15, row = quad*4 + reg.
    #pragma unroll
    for (int j = 0; j < 2; j++) {
        int n = n0 + wn + j * 16 + l16;
        float bv = (flags & 1) ? bias[n] : 0.f;
        bool do_sp = (flags & 4) && (n < 1024);
        float spb = do_sp ? bias[n] : 0.f;
        #pragma unroll
        for (int i = 0; i < 2; i++) {
            int mrow = m0 + wm + i * 16 + quad * 4;
            #pragma unroll
            for (int rr = 0; rr < 4; rr++) {
                size_t idx = (size_t)(mrow + rr) * ldc + n;
                float v = acc[i][j][rr] + bv;
                if (do_sp) {
                    v += spb;
                    v = (v > 20.f) ? v : log1pf(__expf(v));
                }
                if (flags & 8) {
                    Cb[idx] = f2bf(v);
                } else {
                    if (flags & 2) v += C[idx];
                    C[idx] = v;
                }
            }
        }
    }
}

// ---------------------------------------------------------------------------
// build_wdt: Wcat rows 0..1023 = (xw[:, :32] @ dt_w)^T, bf16 [n][k].
// ---------------------------------------------------------------------------
__global__ __launch_bounds__(256) void build_wdt_kernel(
    const float* __restrict__ xproj_w, const float* __restrict__ dt_w,
    ushort_t* __restrict__ wcat)
{
    const int l = blockIdx.z;
    const int n0 = blockIdx.x * 64;
    const int k0 = blockIdx.y * 64;
    const float* xw  = xproj_w + (size_t)l * D_INNER * 64;
    const float* dtw = dt_w + (size_t)l * DT_RANK * D_INNER;

    __shared__ float xs[64][33];   // [k][r]
    __shared__ float ds[32][65];   // [r][n]

    const int tid = threadIdx.x;
    {
        int row = tid >> 2;
        int col = (tid & 3) * 8;
        #pragma unroll
        for (int q = 0; q < 8; q++)
            xs[row][col + q] = xw[(size_t)(k0 + row) * 64 + col + q];
    }
    {
        int row = tid >> 3;
        int col = (tid & 7) * 8;
        #pragma unroll
        for (int q = 0; q < 8; q++)
            ds[row][col + q] = dtw[(size_t)row * D_INNER + n0 + col + q];
    }
    __syncthreads();

    const int ty = tid & 15;
    const int tx = tid >> 4;
    float acc[4][4] = {};
    #pragma unroll
    for (int r = 0; r < 32; r++) {
        float a[4], b[4];
        #pragma unroll
        for (int i = 0; i < 4; i++) a[i] = xs[ty * 4 + i][r];
        #pragma unroll
        for (int j = 0; j < 4; j++) b[j] = ds[r][tx * 4 + j];
        #pragma unroll
        for (int j = 0; j < 4; j++)
            #pragma unroll
            for (int i = 0; i < 4; i++)
                acc[j][i] = fmaf(a[i], b[j], acc[j][i]);
    }
    #pragma unroll
    for (int j = 0; j < 4; j++) {
        int n = n0 + tx * 4 + j;
        ushort4 o;
        o.x = f2bf(acc[j][0]); o.y = f2bf(acc[j][1]);
        o.z = f2bf(acc[j][2]); o.w = f2bf(acc[j][3]);
        *(ushort4*)&wcat[((size_t)l * NCAT + n) * D_INNER + k0 + ty * 4] = o;
    }
}

// ---------------------------------------------------------------------------
// build_wbc: Wcat rows 1024..1151: j<32 -> xw[k][32+j] cast; else zero pad.
// (Pad MUST be written every launch: d_ws is re-poisoned to 0xAA.)
// ---------------------------------------------------------------------------
__global__ __launch_bounds__(256) void build_wbc_kernel(
    const float* __restrict__ xproj_w, ushort_t* __restrict__ wcat)
{
    const int idx = blockIdx.x * 256 + threadIdx.x;
    const int k = idx & 1023;
    const int j = (idx >> 10) & 127;
    const int l = idx >> 17;
    ushort_t v = 0;
    if (j < 32)
        v = f2bf(xproj_w[((size_t)l * D_INNER + k) * 64 + 32 + j]);
    wcat[((size_t)l * NCAT + 1024 + j) * D_INNER + k] = v;
}

// ---------------------------------------------------------------------------
__global__ __launch_bounds__(256) void transpose_cast_kernel(
    const float* __restrict__ in, ushort_t* __restrict__ out, int K, int N)
{
    __shared__ float tile[32][33];
    const int n0 = blockIdx.x * 32, k0 = blockIdx.y * 32;
    const int tx = threadIdx.x & 31, ty = threadIdx.x >> 5;
    #pragma unroll
    for (int i = 0; i < 4; i++)
        tile[ty + i * 8][tx] = in[(size_t)(k0 + ty + i * 8) * N + n0 + tx];
    __syncthreads();
    #pragma unroll
    for (int i = 0; i < 4; i++)
        out[(size_t)(n0 + ty + i * 8) * K + k0 + tx] = f2bf(tile[tx][ty + i * 8]);
}

// ---------------------------------------------------------------------------
__global__ __launch_bounds__(256) void cast_bf16_kernel(
    const float* __restrict__ in, ushort_t* __restrict__ out)
{
    const int i = blockIdx.x * 256 + threadIdx.x;
    out[i] = f2bf(in[i]);
}

// ---------------------------------------------------------------------------
__global__ __launch_bounds__(256) void rmsnorm_kernel(
    const float* __restrict__ x, const float* __restrict__ w,
    ushort_t* __restrict__ y)
{
    const int row = blockIdx.x;
    const float* xr = x + (size_t)row * D_MODEL;
    ushort_t* yr = y + (size_t)row * D_MODEL;
    const int tid = threadIdx.x;

    float v0 = xr[tid], v1 = xr[tid + 256];
    float ss = v0 * v0 + v1 * v1;
    #pragma unroll
    for (int off = 32; off > 0; off >>= 1) ss += __shfl_down(ss, off);

    __shared__ float wsum[4];
    __shared__ float scale_s;
    int wid = tid >> 6, lane = tid & 63;
    if (lane == 0) wsum[wid] = ss;
    __syncthreads();
    if (tid == 0) {
        float tot = wsum[0] + wsum[1] + wsum[2] + wsum[3];
        scale_s = 1.0f / sqrtf(tot / (float)D_MODEL + 1e-5f);
    }
    __syncthreads();
    float sc = scale_s;
    yr[tid] = f2bf(v0 * sc * w[tid]);
    yr[tid + 256] = f2bf(v1 * sc * w[tid + 256]);
}

// ---------------------------------------------------------------------------
// Causal dwconv (K=4) + bias + silu. Reads bf16 xz (stride 2048, xp plane),
// writes bf16 u.
// ---------------------------------------------------------------------------
__global__ __launch_bounds__(256) void conv_silu_kernel(
    const ushort_t* __restrict__ xz, const float* __restrict__ w,
    const float* __restrict__ bconv, ushort_t* __restrict__ outb)
{
    const int idx = blockIdx.x * 256 + threadIdx.x;
    const int d = idx & (D_INNER - 1);
    const int t = (idx >> 10) & (SEQ - 1);
    const int row = idx >> 10;
    const ushort_t* base = xz + (size_t)row * 2048 + d;

    float s = 0.f;
    #pragma unroll
    for (int k = 0; k < KCONV; k++) {
        int tt = t + k - (KCONV - 1);
        if (tt >= 0)
            s = fmaf(bf2f(base[(ptrdiff_t)(k - (KCONV - 1)) * 2048]), w[d * KCONV + k], s);
    }
    s += bconv[d];
    float r = s / (1.f + __expf(-s));
    outb[idx] = f2bf(r);
}

// ---------------------------------------------------------------------------
// Chunked selective scan (3 passes), CLEN=32. dt/B/C in dbl (stride NCAT):
// dbl[row][d]=softplus'ed dt; dbl[row][1024+n]=B[n]; dbl[row][1040+n]=C[n].
// u is bf16 in xb; z is bf16 in xz[:,1024:].
// ---------------------------------------------------------------------------
__global__ __launch_bounds__(256) void scan_pass1(
    const float* __restrict__ dbl, const ushort_t* __restrict__ ub,
    const float* __restrict__ A_log,
    float* __restrict__ hfin, float* __restrict__ sumdt)
{
    const int tid = threadIdx.x;
    const int b = blockIdx.x >> 7;
    const int p = (blockIdx.x >> 2) & 31;
    const int d = ((blockIdx.x & 3) << 8) + tid;
    const int t0 = p * CLEN;

    float A[D_STATE];
    #pragma unroll
    for (int n = 0; n < D_STATE; n++) A[n] = -expf(A_log[d * D_STATE + n]);

    float h[D_STATE] = {};
    float sdt = 0.f;

    const float* dtp = dbl + ((size_t)b * SEQ + t0) * NCAT + d;
    const float* bp  = dbl + ((size_t)b * SEQ + t0) * NCAT + 1024;
    const ushort_t* up = ub + ((size_t)b * SEQ + t0) * D_INNER + d;

    for (int t = 0; t < CLEN; t++) {
        float dtv = dtp[(size_t)t * NCAT];
        float uv  = bf2f(up[(size_t)t * D_INNER]);
        float dtu = dtv * uv;
        sdt += dtv;
        #pragma unroll
        for (int n = 0; n < D_STATE; n++)
            h[n] = fmaf(__expf(dtv * A[n]), h[n], dtu * bp[t * NCAT + n]);
    }

    size_t base = (size_t)(b * PCH + p) * D_STATE * D_INNER + d;
    #pragma unroll
    for (int n = 0; n < D_STATE; n++) hfin[base + (size_t)n * D_INNER] = h[n];
    sumdt[(size_t)(b * PCH + p) * D_INNER + d] = sdt;
}

__global__ __launch_bounds__(256) void scan_pass2(
    const float* __restrict__ A_log, const float* __restrict__ sumdt,
    float* __restrict__ hc)
{
    const int tid = threadIdx.x;
    const int b = blockIdx.x >> 6;
    const int n = (blockIdx.x >> 2) & 15;
    const int d = ((blockIdx.x & 3) << 8) + tid;

    const float Aval = -expf(A_log[d * D_STATE + n]);
    float h = 0.f;
    for (int p = 0; p < PCH; p++) {
        size_t idx = ((size_t)(b * PCH + p) * D_STATE + n) * D_INNER + d;
        float fin = hc[idx];
        hc[idx] = h;
        h = fmaf(__expf(Aval * sumdt[(size_t)(b * PCH + p) * D_INNER + d]), h, fin);
    }
}

// pass3: u (bf16, in ub) read then overwritten IN PLACE with y*silu(z).
__global__ __launch_bounds__(256) void scan_pass3(
    const float* __restrict__ dbl, const ushort_t* __restrict__ xz,
    const float* __restrict__ A_log, const float* __restrict__ Dp,
    const float* __restrict__ hstart, ushort_t* ub)
{
    const int tid = threadIdx.x;
    const int b = blockIdx.x >> 7;
    const int p = (blockIdx.x >> 2) & 31;
    const int d = ((blockIdx.x & 3) << 8) + tid;
    const int t0 = p * CLEN;

    float A[D_STATE];
    #pragma unroll
    for (int n = 0; n < D_STATE; n++) A[n] = -expf(A_log[d * D_STATE + n]);
    const float Dv = Dp[d];

    float h[D_STATE];
    size_t base = (size_t)(b * PCH + p) * D_STATE * D_INNER + d;
    #pragma unroll
    for (int n = 0; n < D_STATE; n++) h[n] = hstart[base + (size_t)n * D_INNER];

    const float* dtp = dbl + ((size_t)b * SEQ + t0) * NCAT + d;
    const float* bp  = dbl + ((size_t)b * SEQ + t0) * NCAT + 1024;
    const ushort_t* zp = xz + ((size_t)b * SEQ + t0) * 2048 + 1024 + d;
    ushort_t* up = ub + ((size_t)b * SEQ + t0) * D_INNER + d;

    for (int t = 0; t < CLEN; t++) {
        float dtv = dtp[(size_t)t * NCAT];
        float uv  = bf2f(up[(size_t)t * D_INNER]);
        float zv  = bf2f(zp[(size_t)t * 2048]);
        float dtu = dtv * uv;
        float y = 0.f;
        #pragma unroll
        for (int n = 0; n < D_STATE; n++) {
            h[n] = fmaf(__expf(dtv * A[n]), h[n], dtu * bp[t * NCAT + n]);
            y = fmaf(h[n], bp[t * NCAT + 16 + n], y);
        }
        float res = fmaf(uv, Dv, y);
        res *= zv / (1.f + __expf(-zv));
        up[(size_t)t * D_INNER] = f2bf(res);
    }
}

// ---------------------------------------------------------------------------
__global__ __launch_bounds__(256) void softmax_kernel(
    const float* __restrict__ in, float* __restrict__ out)
{
    const int idx = blockIdx.x * 256 + threadIdx.x;
    float v = in[idx];
    float m = v;
    #pragma unroll
    for (int off = 16; off > 0; off >>= 1) m = fmaxf(m, __shfl_xor(m, off, 32));
    float e = expf(v - m);
    float s = e;
    #pragma unroll
    for (int off = 16; off > 0; off >>= 1) s += __shfl_xor(s, off, 32);
    out[idx] = e / s;
}

// ---------------------------------------------------------------------------
extern "C" void kernel_launch(void* const* d_in, const int* in_sizes, int n_in,
                              void* d_out, int out_size, void* d_ws, size_t ws_size,
                              hipStream_t stream)
{
    const float* x       = (const float*)d_in[0];
    const float* lin1_w  = (const float*)d_in[1];
    const float* lin1_b  = (const float*)d_in[2];
    const float* norm_w  = (const float*)d_in[3];
    const float* in_w    = (const float*)d_in[4];
    const float* conv_w  = (const float*)d_in[5];
    const float* conv_b  = (const float*)d_in[6];
    const float* xproj_w = (const float*)d_in[7];
    const float* dt_w    = (const float*)d_in[8];
    const float* dt_b    = (const float*)d_in[9];
    const float* A_log   = (const float*)d_in[10];
    const float* Dp      = (const float*)d_in[11];
    const float* out_w   = (const float*)d_in[12];
    const float* lin2_w  = (const float*)d_in[13];
    const float* lin2_b  = (const float*)d_in[14];
    float* outp = (float*)d_out;
    (void)ws_size; (void)in_sizes; (void)n_in; (void)out_size;

    float* ws = (float*)d_ws;
    const size_t F1M = 1u << 20;
    float* h     = ws;                        // 2M fl
    float* dbl   = h + 2 * F1M;               // 4.5M fl (also lin2 logits)
    float* sumdt = dbl + (size_t)NTOK * NCAT; // 128K fl
    float* hfin  = sumdt + (size_t)BATCH * PCH * D_INNER; // 2M fl
    ushort_t* xzb   = (ushort_t*)(hfin + 2 * F1M);        // 8M us (xp|z, 2048)
    ushort_t* hn_bf = xzb + 8 * F1M;                      // 2M us
    ushort_t* xb    = hn_bf + 2 * F1M;                    // 4M us
    ushort_t* lin1_wt = xb + 4 * F1M;                     // 512*1024
    ushort_t* in_wt   = lin1_wt + (size_t)512 * 1024;     // 4*2048*512
    ushort_t* out_wt  = in_wt + (size_t)4 * 2048 * 512;   // 4*512*1024
    ushort_t* lin2_wt = out_wt + (size_t)4 * 512 * 1024;  // 1024*512
    ushort_t* wcat    = lin2_wt + (size_t)1024 * 512;     // 4*1152*1024

    dim3 blk(256);

    // --- weight prep ---
    transpose_cast_kernel<<<dim3(512 / 32, 1024 / 32), blk, 0, stream>>>(
        lin1_w, lin1_wt, LATENT, D_MODEL);
    for (int l = 0; l < N_LAYERS; l++) {
        transpose_cast_kernel<<<dim3(2048 / 32, 512 / 32), blk, 0, stream>>>(
            in_w + (size_t)l * 512 * 2048, in_wt + (size_t)l * 2048 * 512, 512, 2048);
        transpose_cast_kernel<<<dim3(512 / 32, 1024 / 32), blk, 0, stream>>>(
            out_w + (size_t)l * 1024 * 512, out_wt + (size_t)l * 512 * 1024, 1024, 512);
    }
    transpose_cast_kernel<<<dim3(1024 / 32, 512 / 32), blk, 0, stream>>>(
        lin2_w, lin2_wt, D_MODEL, LATENT);
    build_wdt_kernel<<<dim3(16, 16, N_LAYERS), blk, 0, stream>>>(
        xproj_w, dt_w, wcat);
    build_wbc_kernel<<<dim3((N_LAYERS * 128 * 1024) / 256), blk, 0, stream>>>(
        xproj_w, wcat);

    // x -> bf16
    cast_bf16_kernel<<<dim3((NTOK * LATENT) / 256), blk, 0, stream>>>(x, xb);

    // lin1: h = x_bf @ lin1_wt^T + b  (fp32 out), grid 8x64 = 512 blocks
    gemm_bf16_kernel<<<dim3(D_MODEL / 64, NTOK / 64), blk, 0, stream>>>(
        xb, LATENT, lin1_wt, LATENT, h, nullptr, D_MODEL, lin1_b,
        NTOK, D_MODEL, LATENT, 1);

    for (int l = 0; l < N_LAYERS; l++) {
        const float* nw = norm_w + (size_t)l * D_MODEL;
        const float* cw = conv_w + (size_t)l * D_INNER * KCONV;
        const float* cb = conv_b + (size_t)l * D_INNER;
        const float* db = dt_b + (size_t)l * D_INNER;
        const float* al = A_log + (size_t)l * D_INNER * D_STATE;
        const float* dp = Dp + (size_t)l * D_INNER;
        const ushort_t* iwt = in_wt + (size_t)l * 2048 * 512;
        const ushort_t* owt = out_wt + (size_t)l * 512 * 1024;
        const ushort_t* wc  = wcat + (size_t)l * NCAT * D_INNER;

        rmsnorm_kernel<<<dim3(NTOK), blk, 0, stream>>>(h, nw, hn_bf);

        // fused in-proj: xzb = hn @ in_w[l]  (N=2048, bf16 out, 2048 blocks)
        gemm_bf16_kernel<<<dim3(2048 / 64, NTOK / 64), blk, 0, stream>>>(
            hn_bf, D_MODEL, iwt, D_MODEL, nullptr, xzb, 2048, nullptr,
            NTOK, 2048, D_MODEL, 8);

        // conv + silu: xzb[:, :1024] -> xb (bf16 u)
        conv_silu_kernel<<<dim3((NTOK * D_INNER) / 256), blk, 0, stream>>>(
            xzb, cw, cb, xb);

        // merged xproj+dt GEMM: dbl[:, :1024]=softplus(u@Wdt+dt_b),
        //                       dbl[:, 1024:1056]=B|C   (fp32 out, 1152 blocks)
        gemm_bf16_kernel<<<dim3(NCAT / 64, NTOK / 64), blk, 0, stream>>>(
            xb, D_INNER, wc, D_INNER, dbl, nullptr, NCAT, db,
            NTOK, NCAT, D_INNER, 4);

        // chunked scan; pass3 overwrites xb in place with y*silu(z)
        scan_pass1<<<dim3(BATCH * PCH * (D_INNER / 256)), blk, 0, stream>>>(
            dbl, xb, al, hfin, sumdt);
        scan_pass2<<<dim3(BATCH * D_STATE * (D_INNER / 256)), blk, 0, stream>>>(
            al, sumdt, hfin);
        scan_pass3<<<dim3(BATCH * PCH * (D_INNER / 256)), blk, 0, stream>>>(
            dbl, xzb, al, dp, hfin, xb);

        // h += y_bf @ out_wt^T  (fp32 accumulate, 512 blocks)
        gemm_bf16_kernel<<<dim3(D_MODEL / 64, NTOK / 64), blk, 0, stream>>>(
            xb, D_INNER, owt, D_INNER, h, nullptr, D_MODEL, nullptr,
            NTOK, D_MODEL, D_INNER, 2);
    }

    // h -> bf16, lin2 (logits into dbl), softmax
    cast_bf16_kernel<<<dim3((NTOK * D_MODEL) / 256), blk, 0, stream>>>(h, xb);
    gemm_bf16_kernel<<<dim3(LATENT / 64, NTOK / 64), blk, 0, stream>>>(
        xb, D_MODEL, lin2_wt, D_MODEL, dbl, nullptr, LATENT, lin2_b,
        NTOK, LATENT, D_MODEL, 1);
    softmax_kernel<<<dim3((NTOK * LATENT) / 256), blk, 0, stream>>>(dbl, outp);
}